// Round 6
// baseline (176.788 us; speedup 1.0000x reference)
//
#include <hip/hip_runtime.h>
#include <math.h>

#define EPSV 1e-12f

// ---------- Kernel A: partial column sums + per-strip last-block reduction ----------
// grid = (NX, C) where NX = ceil(D4/256). Block (strip, c) sums rows
// [c*rpc, (c+1)*rpc) for float4-cols [strip*256, strip*256+256) into
// partial[c][...]. Then threadfence + ticket; the last block of each strip
// reduces its strip's C partials (fixed order -> deterministic) and writes
// ws6[strip][6] = partial dots {||c||^2, ||i||^2, s.c, s.i, ||s||^2, ||c-i||^2}.
__global__ __launch_bounds__(256)
void ara_colsum_reduce(const float* __restrict__ hid, const float* __restrict__ cdir,
                       const float* __restrict__ idir, float* __restrict__ partial,
                       unsigned int* __restrict__ counters, float* __restrict__ ws6,
                       int D4, int S, int C, int rows_per_chunk) {
    const int tid = threadIdx.x;
    const int strip = blockIdx.x;
    const int c = blockIdx.y;
    const int d4 = strip * 256 + tid;
    const bool valid = (d4 < D4);

    const float4* h4 = reinterpret_cast<const float4*>(hid);
    float4* p4 = reinterpret_cast<float4*>(partial);

    // phase 1: this block's partial column sums
    if (valid) {
        long row0 = (long)c * rows_per_chunk;
        float4 acc = make_float4(0.f, 0.f, 0.f, 0.f);
#pragma unroll 16
        for (int r = 0; r < rows_per_chunk; ++r) {
            long row = row0 + r;
            if (row < S) {
                float4 v = h4[row * (long)D4 + d4];
                acc.x += v.x; acc.y += v.y; acc.z += v.z; acc.w += v.w;
            }
        }
        p4[(long)c * D4 + d4] = acc;
    }
    __threadfence();          // make partial visible device-wide
    __syncthreads();          // all threads of block done before ticket

    __shared__ bool is_last;
    if (tid == 0) {
        unsigned int old = atomicAdd(&counters[strip], 1u);
        is_last = (old == (unsigned int)(C - 1));
    }
    __syncthreads();
    if (!is_last) return;

    // phase 2 (one block per strip): reduce chunks in fixed order
    float4 s = make_float4(0.f, 0.f, 0.f, 0.f);
    if (valid) {
        for (int c2 = 0; c2 < C; ++c2) {
            float4 v = p4[(long)c2 * D4 + d4];
            s.x += v.x; s.y += v.y; s.z += v.z; s.w += v.w;
        }
    }
    float vals[6] = {0.f, 0.f, 0.f, 0.f, 0.f, 0.f};
    if (valid) {
        const float4* c4p = reinterpret_cast<const float4*>(cdir);
        const float4* i4p = reinterpret_cast<const float4*>(idir);
        float4 cv = c4p[d4], iv = i4p[d4];
        vals[0] = cv.x*cv.x + cv.y*cv.y + cv.z*cv.z + cv.w*cv.w;
        vals[1] = iv.x*iv.x + iv.y*iv.y + iv.z*iv.z + iv.w*iv.w;
        vals[2] = s.x*cv.x + s.y*cv.y + s.z*cv.z + s.w*cv.w;
        vals[3] = s.x*iv.x + s.y*iv.y + s.z*iv.z + s.w*iv.w;
        vals[4] = s.x*s.x + s.y*s.y + s.z*s.z + s.w*s.w;
        float dx = cv.x-iv.x, dy = cv.y-iv.y, dz = cv.z-iv.z, dw = cv.w-iv.w;
        vals[5] = dx*dx + dy*dy + dz*dz + dw*dw;
    }
    // block reduction: 4 waves -> LDS -> wave 0
    __shared__ float red[6][4];
    int lane = tid & 63;
    int wid = tid >> 6;
#pragma unroll
    for (int k = 0; k < 6; ++k) {
        float v = vals[k];
#pragma unroll
        for (int o = 32; o > 0; o >>= 1) v += __shfl_down(v, o, 64);
        if (lane == 0) red[k][wid] = v;
    }
    __syncthreads();
    if (tid == 0) {
#pragma unroll
        for (int k = 0; k < 6; ++k)
            ws6[strip * 6 + k] = red[k][0] + red[k][1] + red[k][2] + red[k][3];
    }
}

// ---------- Kernel B: apply ----------
// grid = ceil(S/rows_per_block) x 256. Preamble sums ws6[NX][6] in fixed order,
// computes alpha; main loop streams rows with regular float4 stores.
__global__ __launch_bounds__(256)
void ara_apply(const float* __restrict__ hid, const float* __restrict__ cdir,
               const float* __restrict__ idir, const float* __restrict__ sscale,
               const float* __restrict__ ws6, float* __restrict__ out,
               int D4, int S, int NX, int rows_per_block) {
    __shared__ float bc[3];
    int tid = threadIdx.x;
    if (tid == 0) {
        float t[6] = {0.f, 0.f, 0.f, 0.f, 0.f, 0.f};
        for (int b = 0; b < NX; ++b)
#pragma unroll
            for (int k = 0; k < 6; ++k) t[k] += ws6[b * 6 + k];
        float invS = 1.0f / (float)S;
        float cn = sqrtf(t[4]) * invS;                  // ||mean||
        float inv_cn = 1.0f / fmaxf(cn, EPSV);
        float csim = (sqrtf(t[0]) > 0.f) ? (t[2] * invS * inv_cn) : 0.f;
        float isim = (sqrtf(t[1]) > 0.f) ? (t[3] * invS * inv_cn) : 0.f;
        float quality = csim - isim;
        float amp = 0.5f * (0.1f - quality) / (0.1f + 0.3f);
        float alpha = (quality < -0.3f) ? 0.5f : ((quality < 0.1f) ? amp : 0.05f);
        float ndiff = sqrtf(t[5]);
        float inv_nd = 1.0f / fmaxf(ndiff, EPSV);
        bc[0] = alpha * sscale[0];
        bc[1] = inv_nd;
        bc[2] = ndiff * inv_nd;                         // ||momentum||
    }
    __syncthreads();
    const float a_s = bc[0], inv_nd = bc[1], mnorm = bc[2];
    const float invS = 1.0f / (float)S;

    const float4* h4 = reinterpret_cast<const float4*>(hid);
    const float4* c4p = reinterpret_cast<const float4*>(cdir);
    const float4* i4p = reinterpret_cast<const float4*>(idir);
    float4* o4 = reinterpret_cast<float4*>(out);

    int jn = D4 >> 8;                                   // strips of 256 float4
    float4 mv[4];
    bool cached = (jn <= 4);
    for (int j = 0; j < jn && j < 4; ++j) {
        int d4 = (j << 8) + tid;
        float4 c = c4p[d4], iv = i4p[d4];
        mv[j].x = (c.x - iv.x) * inv_nd;
        mv[j].y = (c.y - iv.y) * inv_nd;
        mv[j].z = (c.z - iv.z) * inv_nd;
        mv[j].w = (c.w - iv.w) * inv_nd;
    }
    long row0 = (long)blockIdx.x * rows_per_block;
    for (int r = 0; r < rows_per_block; ++r) {
        long s = row0 + r;
        if (s >= S) break;
        float eff = a_s * (0.5f + 0.5f * ((float)s * invS));
        float dn = fabsf(eff) * mnorm;
        float coef = (dn > 0.5f) ? (eff * (0.5f / dn)) : eff;
        for (int j = 0; j < jn; ++j) {
            long idx = s * (long)D4 + (j << 8) + tid;
            float4 m;
            if (cached) {
                m = mv[j];
            } else {
                int d4 = (j << 8) + tid;
                float4 c = c4p[d4], iv = i4p[d4];
                m.x = (c.x - iv.x) * inv_nd; m.y = (c.y - iv.y) * inv_nd;
                m.z = (c.z - iv.z) * inv_nd; m.w = (c.w - iv.w) * inv_nd;
            }
            float4 h = h4[idx];
            float4 rr;
            rr.x = h.x + coef * m.x;
            rr.y = h.y + coef * m.y;
            rr.z = h.z + coef * m.z;
            rr.w = h.w + coef * m.w;
            o4[idx] = rr;
        }
    }
}

extern "C" void kernel_launch(void* const* d_in, const int* in_sizes, int n_in,
                              void* d_out, int out_size, void* d_ws, size_t ws_size,
                              hipStream_t stream) {
    const float* hid    = (const float*)d_in[0];
    const float* cdir   = (const float*)d_in[1];
    const float* idir   = (const float*)d_in[2];
    const float* sscale = (const float*)d_in[3];
    float* out = (float*)d_out;

    int D = in_sizes[1];                 // 4096
    long total = (long)in_sizes[0];      // B*S*D, B=1
    int S = (int)(total / D);            // 8192
    int D4 = D / 4;
    int NX = (D4 + 255) / 256;           // 4 strips for D=4096

    const int C = 128;                   // chunks along S
    int rows_per_chunk = (S + C - 1) / C;

    float* partial = (float*)d_ws;                            // C*D floats
    unsigned int* counters = (unsigned int*)(partial + (size_t)C * D);  // NX uints
    float* ws6 = (float*)(counters + NX);                     // NX*6 floats

    hipMemsetAsync(counters, 0, NX * sizeof(unsigned int), stream);

    dim3 g1(NX, C);
    ara_colsum_reduce<<<g1, 256, 0, stream>>>(hid, cdir, idir, partial,
                                              counters, ws6, D4, S, C, rows_per_chunk);

    int rows_per_block = 2;
    int g3 = (S + rows_per_block - 1) / rows_per_block;  // 4096
    ara_apply<<<g3, 256, 0, stream>>>(hid, cdir, idir, sscale, ws6, out,
                                      D4, S, NX, rows_per_block);
}

// Round 7
// 98.244 us; speedup vs baseline: 1.7995x; 1.7995x over previous
//
#include <hip/hip_runtime.h>
#include <math.h>

#define EPSV 1e-12f

// ---------- Kernel 1: partial column sums (deterministic, no atomics, no fences) ----------
// grid = (NX, C), NX = ceil(D4/256). Block (strip, c) sums its strip's 256
// float4-cols over rows [c*rpc, c*rpc+rpc_eff) into partial[c][...].
__global__ __launch_bounds__(256)
void ara_colsum(const float* __restrict__ hid, float* __restrict__ partial,
                int D4, int S, int rows_per_chunk) {
    int d4 = blockIdx.x * 256 + threadIdx.x;
    if (d4 >= D4) return;
    int c = blockIdx.y;
    const float4* h4 = reinterpret_cast<const float4*>(hid);
    float4* p4 = reinterpret_cast<float4*>(partial);
    long row0 = (long)c * rows_per_chunk;
    int rpc_eff = rows_per_chunk;
    if (row0 + rpc_eff > S) rpc_eff = (int)(S - row0);
    const float4* p = h4 + row0 * (long)D4 + d4;
    float4 acc = make_float4(0.f, 0.f, 0.f, 0.f);
#pragma unroll 8
    for (int r = 0; r < rpc_eff; ++r) {
        float4 v = p[(long)r * D4];
        acc.x += v.x; acc.y += v.y; acc.z += v.z; acc.w += v.w;
    }
    p4[(long)c * D4 + d4] = acc;
}

// ---------- Kernel 2: reduce partials + 6 dot products ----------
// grid = NB = ceil(D4/64) blocks x 256 threads. Block b owns float4 cols
// [b*64, b*64+64). 4 thread-groups of 64 lanes each sum C/4 chunks.
// ws6[b][6] = {||c||^2, ||i||^2, s.c, s.i, ||s||^2, ||c-i||^2} partials.
__global__ __launch_bounds__(256)
void ara_reduce(const float* __restrict__ partial, const float* __restrict__ cdir,
                const float* __restrict__ idir, float* __restrict__ ws6,
                int D4, int C) {
    const float4* p4 = reinterpret_cast<const float4*>(partial);
    const float4* c4p = reinterpret_cast<const float4*>(cdir);
    const float4* i4p = reinterpret_cast<const float4*>(idir);
    int lane = threadIdx.x & 63;
    int g = threadIdx.x >> 6;                 // 0..3
    int col = blockIdx.x * 64 + lane;
    bool valid = col < D4;
    int per = (C + 3) / 4;
    float4 acc = make_float4(0.f, 0.f, 0.f, 0.f);
    if (valid) {
        for (int j = 0; j < per; ++j) {
            int c = g * per + j;
            if (c < C) {
                float4 v = p4[(long)c * D4 + col];
                acc.x += v.x; acc.y += v.y; acc.z += v.z; acc.w += v.w;
            }
        }
    }
    __shared__ float4 lds[4][64];
    lds[g][lane] = acc;
    __syncthreads();
    if (threadIdx.x < 64) {
        float vals[6] = {0.f, 0.f, 0.f, 0.f, 0.f, 0.f};
        if (valid) {
            float4 s;
            s.x = lds[0][lane].x + lds[1][lane].x + lds[2][lane].x + lds[3][lane].x;
            s.y = lds[0][lane].y + lds[1][lane].y + lds[2][lane].y + lds[3][lane].y;
            s.z = lds[0][lane].z + lds[1][lane].z + lds[2][lane].z + lds[3][lane].z;
            s.w = lds[0][lane].w + lds[1][lane].w + lds[2][lane].w + lds[3][lane].w;
            float4 c = c4p[col], iv = i4p[col];
            vals[0] = c.x*c.x + c.y*c.y + c.z*c.z + c.w*c.w;
            vals[1] = iv.x*iv.x + iv.y*iv.y + iv.z*iv.z + iv.w*iv.w;
            vals[2] = s.x*c.x + s.y*c.y + s.z*c.z + s.w*c.w;
            vals[3] = s.x*iv.x + s.y*iv.y + s.z*iv.z + s.w*iv.w;
            vals[4] = s.x*s.x + s.y*s.y + s.z*s.z + s.w*s.w;
            float dx = c.x-iv.x, dy = c.y-iv.y, dz = c.z-iv.z, dw = c.w-iv.w;
            vals[5] = dx*dx + dy*dy + dz*dz + dw*dw;
        }
#pragma unroll
        for (int k = 0; k < 6; ++k) {
            float v = vals[k];
#pragma unroll
            for (int o = 32; o > 0; o >>= 1) v += __shfl_down(v, o, 64);
            if (lane == 0) ws6[blockIdx.x * 6 + k] = v;
        }
    }
}

// ---------- Kernel 3: apply ----------
// grid = ceil(S/rows_per_block) x 256. Preamble sums ws6[NB][6] in fixed order
// -> alpha; main loop streams rows with regular float4 stores.
__global__ __launch_bounds__(256)
void ara_apply(const float* __restrict__ hid, const float* __restrict__ cdir,
               const float* __restrict__ idir, const float* __restrict__ sscale,
               const float* __restrict__ ws6, float* __restrict__ out,
               int D4, int S, int NB, int rows_per_block) {
    __shared__ float bc[3];
    int tid = threadIdx.x;
    if (tid == 0) {
        float t[6] = {0.f, 0.f, 0.f, 0.f, 0.f, 0.f};
        for (int b = 0; b < NB; ++b)
#pragma unroll
            for (int k = 0; k < 6; ++k) t[k] += ws6[b * 6 + k];
        float invS = 1.0f / (float)S;
        float cn = sqrtf(t[4]) * invS;                  // ||mean||
        float inv_cn = 1.0f / fmaxf(cn, EPSV);
        float csim = (sqrtf(t[0]) > 0.f) ? (t[2] * invS * inv_cn) : 0.f;
        float isim = (sqrtf(t[1]) > 0.f) ? (t[3] * invS * inv_cn) : 0.f;
        float quality = csim - isim;
        float amp = 0.5f * (0.1f - quality) / (0.1f + 0.3f);
        float alpha = (quality < -0.3f) ? 0.5f : ((quality < 0.1f) ? amp : 0.05f);
        float ndiff = sqrtf(t[5]);
        float inv_nd = 1.0f / fmaxf(ndiff, EPSV);
        bc[0] = alpha * sscale[0];
        bc[1] = inv_nd;
        bc[2] = ndiff * inv_nd;                         // ||momentum||
    }
    __syncthreads();
    const float a_s = bc[0], inv_nd = bc[1], mnorm = bc[2];
    const float invS = 1.0f / (float)S;

    const float4* h4 = reinterpret_cast<const float4*>(hid);
    const float4* c4p = reinterpret_cast<const float4*>(cdir);
    const float4* i4p = reinterpret_cast<const float4*>(idir);
    float4* o4 = reinterpret_cast<float4*>(out);

    int jn = D4 >> 8;                                   // strips of 256 float4
    float4 mv[4];
    bool cached = (jn <= 4);
    for (int j = 0; j < jn && j < 4; ++j) {
        int d4 = (j << 8) + tid;
        float4 c = c4p[d4], iv = i4p[d4];
        mv[j].x = (c.x - iv.x) * inv_nd;
        mv[j].y = (c.y - iv.y) * inv_nd;
        mv[j].z = (c.z - iv.z) * inv_nd;
        mv[j].w = (c.w - iv.w) * inv_nd;
    }
    long row0 = (long)blockIdx.x * rows_per_block;
    for (int r = 0; r < rows_per_block; ++r) {
        long s = row0 + r;
        if (s >= S) break;
        float eff = a_s * (0.5f + 0.5f * ((float)s * invS));
        float dn = fabsf(eff) * mnorm;
        float coef = (dn > 0.5f) ? (eff * (0.5f / dn)) : eff;
        for (int j = 0; j < jn; ++j) {
            long idx = s * (long)D4 + (j << 8) + tid;
            float4 m;
            if (cached) {
                m = mv[j];
            } else {
                int d4 = (j << 8) + tid;
                float4 c = c4p[d4], iv = i4p[d4];
                m.x = (c.x - iv.x) * inv_nd; m.y = (c.y - iv.y) * inv_nd;
                m.z = (c.z - iv.z) * inv_nd; m.w = (c.w - iv.w) * inv_nd;
            }
            float4 h = h4[idx];
            float4 rr;
            rr.x = h.x + coef * m.x;
            rr.y = h.y + coef * m.y;
            rr.z = h.z + coef * m.z;
            rr.w = h.w + coef * m.w;
            o4[idx] = rr;
        }
    }
}

extern "C" void kernel_launch(void* const* d_in, const int* in_sizes, int n_in,
                              void* d_out, int out_size, void* d_ws, size_t ws_size,
                              hipStream_t stream) {
    const float* hid    = (const float*)d_in[0];
    const float* cdir   = (const float*)d_in[1];
    const float* idir   = (const float*)d_in[2];
    const float* sscale = (const float*)d_in[3];
    float* out = (float*)d_out;

    int D = in_sizes[1];                 // 4096
    long total = (long)in_sizes[0];      // B*S*D, B=1
    int S = (int)(total / D);            // 8192
    int D4 = D / 4;
    int NX = (D4 + 255) / 256;           // 4 strips for D=4096

    const int C = 256;                   // chunks along S (1024 blocks)
    int rows_per_chunk = (S + C - 1) / C;

    float* partial = (float*)d_ws;                       // C*D floats (4 MB)
    float* ws6 = partial + (size_t)C * D;                // NB*6 floats

    dim3 g1(NX, C);
    ara_colsum<<<g1, 256, 0, stream>>>(hid, partial, D4, S, rows_per_chunk);

    int NB = (D4 + 63) / 64;             // 16 for D=4096
    ara_reduce<<<NB, 256, 0, stream>>>(partial, cdir, idir, ws6, D4, C);

    int rows_per_block = 2;
    int g3 = (S + rows_per_block - 1) / rows_per_block;  // 4096
    ara_apply<<<g3, 256, 0, stream>>>(hid, cdir, idir, sscale, ws6, out,
                                      D4, S, NB, rows_per_block);
}

// Round 8
// 97.157 us; speedup vs baseline: 1.8196x; 1.0112x over previous
//
#include <hip/hip_runtime.h>
#include <math.h>

#define EPSV 1e-12f

// ---------- Kernel 1: partial column sums, contiguous row-chunk blocks ----------
// grid = C blocks. Block c owns rows [c*rpc, c*rpc+rpc_eff) — a fully
// contiguous 512 KB region. Thread t accumulates float4-columns
// t, t+256, t+512, t+768 (G=D4/256 groups). partial[c][D].
__global__ __launch_bounds__(256)
void ara_colsum(const float* __restrict__ hid, float* __restrict__ partial,
                int D4, int S, int rows_per_chunk) {
    const int tid = threadIdx.x;
    const int c = blockIdx.x;
    const float4* h4 = reinterpret_cast<const float4*>(hid);
    float4* p4 = reinterpret_cast<float4*>(partial);
    long row0 = (long)c * rows_per_chunk;
    int rpc_eff = rows_per_chunk;
    if (row0 + rpc_eff > S) rpc_eff = (int)(S - row0);
    const float4* base = h4 + row0 * (long)D4;
    const int G = D4 >> 8;               // col groups of 256 float4

    if (G == 4) {                        // fast path (D = 4096)
        float4 a0 = make_float4(0.f,0.f,0.f,0.f), a1 = a0, a2 = a0, a3 = a0;
        for (int r = 0; r < rpc_eff; ++r) {
            const float4* row = base + (long)r * D4;
            float4 v0 = row[tid];
            float4 v1 = row[tid + 256];
            float4 v2 = row[tid + 512];
            float4 v3 = row[tid + 768];
            a0.x += v0.x; a0.y += v0.y; a0.z += v0.z; a0.w += v0.w;
            a1.x += v1.x; a1.y += v1.y; a1.z += v1.z; a1.w += v1.w;
            a2.x += v2.x; a2.y += v2.y; a2.z += v2.z; a2.w += v2.w;
            a3.x += v3.x; a3.y += v3.y; a3.z += v3.z; a3.w += v3.w;
        }
        float4* dst = p4 + (long)c * D4;
        dst[tid]       = a0;
        dst[tid + 256] = a1;
        dst[tid + 512] = a2;
        dst[tid + 768] = a3;
    } else {                             // generic: one group at a time
        for (int g = 0; g < G; ++g) {
            float4 acc = make_float4(0.f,0.f,0.f,0.f);
            int col = (g << 8) + tid;
            for (int r = 0; r < rpc_eff; ++r) {
                float4 v = base[(long)r * D4 + col];
                acc.x += v.x; acc.y += v.y; acc.z += v.z; acc.w += v.w;
            }
            p4[(long)c * D4 + col] = acc;
        }
    }
}

// ---------- Kernel 2: reduce partials + 6 dot products ----------
// grid = NB = ceil(D4/64) blocks x 256 threads. Block b owns float4 cols
// [b*64, b*64+64). 4 groups of 64 lanes each sum C/4 chunks.
// ws6[b][6] = {||c||^2, ||i||^2, s.c, s.i, ||s||^2, ||c-i||^2} partials.
__global__ __launch_bounds__(256)
void ara_reduce(const float* __restrict__ partial, const float* __restrict__ cdir,
                const float* __restrict__ idir, float* __restrict__ ws6,
                int D4, int C) {
    const float4* p4 = reinterpret_cast<const float4*>(partial);
    const float4* c4p = reinterpret_cast<const float4*>(cdir);
    const float4* i4p = reinterpret_cast<const float4*>(idir);
    int lane = threadIdx.x & 63;
    int g = threadIdx.x >> 6;                 // 0..3
    int col = blockIdx.x * 64 + lane;
    bool valid = col < D4;
    int per = (C + 3) / 4;
    float4 acc = make_float4(0.f, 0.f, 0.f, 0.f);
    if (valid) {
        for (int j = 0; j < per; ++j) {
            int c = g * per + j;
            if (c < C) {
                float4 v = p4[(long)c * D4 + col];
                acc.x += v.x; acc.y += v.y; acc.z += v.z; acc.w += v.w;
            }
        }
    }
    __shared__ float4 lds[4][64];
    lds[g][lane] = acc;
    __syncthreads();
    if (threadIdx.x < 64) {
        float vals[6] = {0.f, 0.f, 0.f, 0.f, 0.f, 0.f};
        if (valid) {
            float4 s;
            s.x = lds[0][lane].x + lds[1][lane].x + lds[2][lane].x + lds[3][lane].x;
            s.y = lds[0][lane].y + lds[1][lane].y + lds[2][lane].y + lds[3][lane].y;
            s.z = lds[0][lane].z + lds[1][lane].z + lds[2][lane].z + lds[3][lane].z;
            s.w = lds[0][lane].w + lds[1][lane].w + lds[2][lane].w + lds[3][lane].w;
            float4 c = c4p[col], iv = i4p[col];
            vals[0] = c.x*c.x + c.y*c.y + c.z*c.z + c.w*c.w;
            vals[1] = iv.x*iv.x + iv.y*iv.y + iv.z*iv.z + iv.w*iv.w;
            vals[2] = s.x*c.x + s.y*c.y + s.z*c.z + s.w*c.w;
            vals[3] = s.x*iv.x + s.y*iv.y + s.z*iv.z + s.w*iv.w;
            vals[4] = s.x*s.x + s.y*s.y + s.z*s.z + s.w*s.w;
            float dx = c.x-iv.x, dy = c.y-iv.y, dz = c.z-iv.z, dw = c.w-iv.w;
            vals[5] = dx*dx + dy*dy + dz*dz + dw*dw;
        }
#pragma unroll
        for (int k = 0; k < 6; ++k) {
            float v = vals[k];
#pragma unroll
            for (int o = 32; o > 0; o >>= 1) v += __shfl_down(v, o, 64);
            if (lane == 0) ws6[blockIdx.x * 6 + k] = v;
        }
    }
}

// ---------- Kernel 3: apply ----------
// grid = ceil(S/rows_per_block) x 256. Parallel preamble loads ws6[NB][6]
// (96 floats) via 96 threads -> LDS; tid0 folds -> alpha. Main loop streams
// rows with regular float4 stores.
__global__ __launch_bounds__(256)
void ara_apply(const float* __restrict__ hid, const float* __restrict__ cdir,
               const float* __restrict__ idir, const float* __restrict__ sscale,
               const float* __restrict__ ws6, float* __restrict__ out,
               int D4, int S, int NB, int rows_per_block) {
    __shared__ float sv[256];
    __shared__ float bc[3];
    int tid = threadIdx.x;
    int n6 = NB * 6;
    if (tid < n6 && tid < 256) sv[tid] = ws6[tid];
    __syncthreads();
    if (tid == 0) {
        float t[6] = {0.f, 0.f, 0.f, 0.f, 0.f, 0.f};
        for (int b = 0; b < NB; ++b)
#pragma unroll
            for (int k = 0; k < 6; ++k) t[k] += sv[b * 6 + k];
        float invS = 1.0f / (float)S;
        float cn = sqrtf(t[4]) * invS;                  // ||mean||
        float inv_cn = 1.0f / fmaxf(cn, EPSV);
        float csim = (sqrtf(t[0]) > 0.f) ? (t[2] * invS * inv_cn) : 0.f;
        float isim = (sqrtf(t[1]) > 0.f) ? (t[3] * invS * inv_cn) : 0.f;
        float quality = csim - isim;
        float amp = 0.5f * (0.1f - quality) / (0.1f + 0.3f);
        float alpha = (quality < -0.3f) ? 0.5f : ((quality < 0.1f) ? amp : 0.05f);
        float ndiff = sqrtf(t[5]);
        float inv_nd = 1.0f / fmaxf(ndiff, EPSV);
        bc[0] = alpha * sscale[0];
        bc[1] = inv_nd;
        bc[2] = ndiff * inv_nd;                         // ||momentum||
    }
    __syncthreads();
    const float a_s = bc[0], inv_nd = bc[1], mnorm = bc[2];
    const float invS = 1.0f / (float)S;

    const float4* h4 = reinterpret_cast<const float4*>(hid);
    const float4* c4p = reinterpret_cast<const float4*>(cdir);
    const float4* i4p = reinterpret_cast<const float4*>(idir);
    float4* o4 = reinterpret_cast<float4*>(out);

    int jn = D4 >> 8;                                   // strips of 256 float4
    float4 mv[4];
    bool cached = (jn <= 4);
    for (int j = 0; j < jn && j < 4; ++j) {
        int d4 = (j << 8) + tid;
        float4 c = c4p[d4], iv = i4p[d4];
        mv[j].x = (c.x - iv.x) * inv_nd;
        mv[j].y = (c.y - iv.y) * inv_nd;
        mv[j].z = (c.z - iv.z) * inv_nd;
        mv[j].w = (c.w - iv.w) * inv_nd;
    }
    long row0 = (long)blockIdx.x * rows_per_block;
    for (int r = 0; r < rows_per_block; ++r) {
        long s = row0 + r;
        if (s >= S) break;
        float eff = a_s * (0.5f + 0.5f * ((float)s * invS));
        float dn = fabsf(eff) * mnorm;
        float coef = (dn > 0.5f) ? (eff * (0.5f / dn)) : eff;
        for (int j = 0; j < jn; ++j) {
            long idx = s * (long)D4 + (j << 8) + tid;
            float4 m;
            if (cached) {
                m = mv[j];
            } else {
                int d4 = (j << 8) + tid;
                float4 c = c4p[d4], iv = i4p[d4];
                m.x = (c.x - iv.x) * inv_nd; m.y = (c.y - iv.y) * inv_nd;
                m.z = (c.z - iv.z) * inv_nd; m.w = (c.w - iv.w) * inv_nd;
            }
            float4 h = h4[idx];
            float4 rr;
            rr.x = h.x + coef * m.x;
            rr.y = h.y + coef * m.y;
            rr.z = h.z + coef * m.z;
            rr.w = h.w + coef * m.w;
            o4[idx] = rr;
        }
    }
}

extern "C" void kernel_launch(void* const* d_in, const int* in_sizes, int n_in,
                              void* d_out, int out_size, void* d_ws, size_t ws_size,
                              hipStream_t stream) {
    const float* hid    = (const float*)d_in[0];
    const float* cdir   = (const float*)d_in[1];
    const float* idir   = (const float*)d_in[2];
    const float* sscale = (const float*)d_in[3];
    float* out = (float*)d_out;

    int D = in_sizes[1];                 // 4096
    long total = (long)in_sizes[0];      // B*S*D, B=1
    int S = (int)(total / D);            // 8192
    int D4 = D / 4;

    const int C = 256;                   // row chunks (256 blocks, 32 rows each)
    int rows_per_chunk = (S + C - 1) / C;

    float* partial = (float*)d_ws;                       // C*D floats (4 MB)
    float* ws6 = partial + (size_t)C * D;                // NB*6 floats

    ara_colsum<<<C, 256, 0, stream>>>(hid, partial, D4, S, rows_per_chunk);

    int NB = (D4 + 63) / 64;             // 16 for D=4096
    ara_reduce<<<NB, 256, 0, stream>>>(partial, cdir, idir, ws6, D4, C);

    int rows_per_block = 2;
    int g3 = (S + rows_per_block - 1) / rows_per_block;  // 4096
    ara_apply<<<g3, 256, 0, stream>>>(hid, cdir, idir, sscale, ws6, out,
                                      D4, S, NB, rows_per_block);
}